// Round 15
// baseline (585.470 us; speedup 1.0000x reference)
//
#include <hip/hip_runtime.h>
#include <hip/hip_bf16.h>

typedef __bf16 bf16_t;
typedef __attribute__((ext_vector_type(8))) __bf16 bf16x8;
typedef __attribute__((ext_vector_type(4))) __bf16 bf16x4;
typedef __attribute__((ext_vector_type(4))) float f32x4;

#define B_ 2
#define S_ 2048
#define D_ 7168
#define R_ 1024
#define H_ 16
#define VD_ 128
#define MROWS 4096   // B_*S_
#define NQKV 2048    // fused q|kv cols
#define HVD 2048     // H_*VD_

// ---------------- async global->LDS, 16B per lane ----------------
__device__ __forceinline__ void gload_lds16(const bf16_t* g, bf16_t* l) {
    __builtin_amdgcn_global_load_lds(
        (const __attribute__((address_space(1))) unsigned int*)(g),
        (__attribute__((address_space(3))) unsigned int*)(l),
        16, 0, 0);
}

// ---------------- fused f32 -> bf16 conversion, all 5 tensors, 1 launch -------
__global__ __launch_bounds__(256)
void cvt_fused(const float* __restrict__ x,  const float* __restrict__ Wq,
               const float* __restrict__ Wkv, const float* __restrict__ Wvb,
               const float* __restrict__ Wo,
               bf16_t* __restrict__ xb, bf16_t* __restrict__ Wqkv_b,
               bf16_t* __restrict__ Wvb_b, bf16_t* __restrict__ Wo_b,
               float inv_scale)
{
    const long c = ((long)blockIdx.x * 256 + threadIdx.x);   // chunk of 8
    const long e = c * 8;                                    // element index
    const float* src; bf16_t* dst; long off; float scale = 1.0f;
    if (e < 29360128L) {                 // x -> xb
        src = x;   dst = xb;              off = e;
    } else if (e < 36700160L) {          // Wq -> Wqkv_b[0:] (scaled)
        src = Wq;  dst = Wqkv_b;          off = e - 29360128L; scale = inv_scale;
    } else if (e < 44040192L) {          // Wkv -> Wqkv_b[7340032:]
        src = Wkv; dst = Wqkv_b + 7340032; off = e - 36700160L;
    } else if (e < 46137344L) {          // Wvb -> Wvb_b
        src = Wvb; dst = Wvb_b;           off = e - 44040192L;
    } else {                             // Wo -> Wo_b
        src = Wo;  dst = Wo_b;            off = e - 46137344L;
    }
    f32x4 v0 = *(const f32x4*)(src + off);
    f32x4 v1 = *(const f32x4*)(src + off + 4);
    bf16x8 o;
    o[0] = (bf16_t)(v0[0] * scale); o[1] = (bf16_t)(v0[1] * scale);
    o[2] = (bf16_t)(v0[2] * scale); o[3] = (bf16_t)(v0[3] * scale);
    o[4] = (bf16_t)(v1[0] * scale); o[5] = (bf16_t)(v1[1] * scale);
    o[6] = (bf16_t)(v1[2] * scale); o[7] = (bf16_t)(v1[3] * scale);
    *(bf16x8*)(dst + off) = o;
}

// ---------------- bf16 GEMM 128x128 (R8 schedule: best for 4-wave) ------------
template<int OUTF32>
__global__ __launch_bounds__(256)
void gemm_bt(const bf16_t* __restrict__ A, int lda,
             const bf16_t* __restrict__ Bt, int ldb,
             void* __restrict__ Cv, int ldc,
             const float* __restrict__ bias, int K)
{
    __shared__ __align__(16) bf16_t As[2][128 * 64];
    __shared__ __align__(16) bf16_t Bs[2][128 * 64];
    const int tid  = threadIdx.x;
    const int lane = tid & 63;
    const int wave = tid >> 6;
    const int tileM = blockIdx.y * 128;
    const int tileN = blockIdx.x * 128;
    const int wr = (wave >> 1) * 64;
    const int wc = (wave & 1) * 64;
    const int r  = lane & 15;
    const int kq = lane >> 4;

    const bf16_t* Ag = A  + (size_t)tileM * lda;
    const bf16_t* Bg = Bt + (size_t)tileN * ldb;

    int srow[4], scol[4], slin[4];
    #pragma unroll
    for (int i = 0; i < 4; ++i) {
        slin[i] = (i * 256 + tid) * 8;
        srow[i] = slin[i] >> 6;
        scol[i] = (slin[i] & 63) ^ ((srow[i] & 7) << 3);  // inverse-swizzled source
    }

    #define ISSUE_TILE(buf, k0)                                                  \
        {                                                                        \
            _Pragma("unroll")                                                    \
            for (int i = 0; i < 4; ++i) {                                        \
                gload_lds16(Ag + (size_t)srow[i] * lda + (k0) + scol[i], As[buf] + slin[i]); \
                gload_lds16(Bg + (size_t)srow[i] * ldb + (k0) + scol[i], Bs[buf] + slin[i]); \
            }                                                                    \
        }

    f32x4 acc[4][4] = {};
    const int nt = K >> 6;

    ISSUE_TILE(0, 0)
    ISSUE_TILE(1, 64)
    asm volatile("s_waitcnt vmcnt(8)" ::: "memory");
    __builtin_amdgcn_s_barrier();
    __builtin_amdgcn_sched_barrier(0);

    for (int t = 0; t < nt; ++t) {
        const int cur = t & 1;
        const bf16_t* Ab = As[cur];
        const bf16_t* Bb = Bs[cur];

        bf16x8 af[4][2], bfr[4][2];
        #pragma unroll
        for (int m = 0; m < 4; ++m)
            #pragma unroll
            for (int kk = 0; kk < 2; ++kk) {
                const int e = (wr + m * 16 + r) * 64 + kk * 32 + kq * 8;
                af[m][kk] = *(const bf16x8*)(Ab + (e ^ ((r & 7) << 3)));
            }
        #pragma unroll
        for (int n = 0; n < 4; ++n)
            #pragma unroll
            for (int kk = 0; kk < 2; ++kk) {
                const int e = (wc + n * 16 + r) * 64 + kk * 32 + kq * 8;
                bfr[n][kk] = *(const bf16x8*)(Bb + (e ^ ((r & 7) << 3)));
            }
        __builtin_amdgcn_s_setprio(1);
        #pragma unroll
        for (int kk = 0; kk < 2; ++kk)
            #pragma unroll
            for (int m = 0; m < 4; ++m)
                #pragma unroll
                for (int n = 0; n < 4; ++n)
                    acc[m][n] = __builtin_amdgcn_mfma_f32_16x16x32_bf16(af[m][kk], bfr[n][kk], acc[m][n], 0, 0, 0);
        __builtin_amdgcn_s_setprio(0);

        __builtin_amdgcn_s_barrier();
        __builtin_amdgcn_sched_barrier(0);
        if (t + 2 < nt) {
            ISSUE_TILE(cur, (t + 2) << 6)
            asm volatile("s_waitcnt vmcnt(8)" ::: "memory");
        } else {
            asm volatile("s_waitcnt vmcnt(0)" ::: "memory");
        }
        __builtin_amdgcn_s_barrier();
        __builtin_amdgcn_sched_barrier(0);
    }
    #undef ISSUE_TILE

    const int orow = tileM + wr + kq * 4;
    const int ocol = tileN + wc + r;
    if (OUTF32) {
        float* C = (float*)Cv;
        #pragma unroll
        for (int n = 0; n < 4; ++n) {
            float bv = bias[ocol + n * 16];
            #pragma unroll
            for (int m = 0; m < 4; ++m)
                #pragma unroll
                for (int j = 0; j < 4; ++j)
                    C[(size_t)(orow + m * 16 + j) * ldc + ocol + n * 16] = acc[m][n][j] + bv;
        }
    } else {
        bf16_t* C = (bf16_t*)Cv;
        #pragma unroll
        for (int m = 0; m < 4; ++m)
            #pragma unroll
            for (int n = 0; n < 4; ++n)
                #pragma unroll
                for (int j = 0; j < 4; ++j)
                    C[(size_t)(orow + m * 16 + j) * ldc + ocol + n * 16] = (bf16_t)acc[m][n][j];
    }
}

// ---------------- bf16 GEMM 256x256, 8-phase m201-style schedule (R14) --------
template<int OUTF32>
__global__ __launch_bounds__(512, 2)
void gemm_bt256p(const bf16_t* __restrict__ A, int lda,
                 const bf16_t* __restrict__ Bt, int ldb,
                 void* __restrict__ Cv, int ldc,
                 const float* __restrict__ bias, int K)
{
    __shared__ __align__(16) bf16_t As[2][256 * 64];
    __shared__ __align__(16) bf16_t Bs[2][256 * 64];
    const int tid  = threadIdx.x;
    const int lane = tid & 63;
    const int wave = tid >> 6;
    const int wm = wave >> 2;          // 0..1 -> M offset wm*128
    const int wn = wave & 3;           // 0..3 -> N offset wn*64
    const int tileM = blockIdx.y * 256;
    const int tileN = blockIdx.x * 256;
    const int r  = lane & 15;
    const int kq = lane >> 4;

    const bf16_t* Ag = A  + (size_t)tileM * lda;
    const bf16_t* Bg = Bt + (size_t)tileN * ldb;

    int sr[2], sc[2], sl[2];
    #pragma unroll
    for (int i = 0; i < 2; ++i) {
        sl[i] = (i * 512 + tid) * 8;
        sr[i] = sl[i] >> 6;
        sc[i] = (sl[i] & 63) ^ ((sr[i] & 7) << 3);   // inverse-swizzled source
    }

    #define STA(buf, k0, h)                                                      \
        { _Pragma("unroll")                                                      \
          for (int i = 0; i < 2; ++i)                                            \
              gload_lds16(Ag + (size_t)((h) * 128 + sr[i]) * lda + (k0) + sc[i], \
                          As[buf] + (h) * 8192 + sl[i]); }
    #define STB(buf, k0, h)                                                      \
        { _Pragma("unroll")                                                      \
          for (int i = 0; i < 2; ++i)                                            \
              gload_lds16(Bg + (size_t)((h) * 128 + sr[i]) * ldb + (k0) + sc[i], \
                          Bs[buf] + (h) * 8192 + sl[i]); }

    #define PHASE(buf, q, READB, STAGE_STMT, VM_STMT)                            \
        {                                                                        \
            const bf16_t* Ab_ = As[buf];                                         \
            const bf16_t* Bb_ = Bs[buf];                                         \
            bf16x8 af_[2][2];                                                    \
            _Pragma("unroll")                                                    \
            for (int mm = 0; mm < 2; ++mm)                                       \
                _Pragma("unroll")                                                \
                for (int kk = 0; kk < 2; ++kk) {                                 \
                    const int e = (wm * 128 + ((q) * 2 + mm) * 16 + r) * 64 + kk * 32 + kq * 8; \
                    af_[mm][kk] = *(const bf16x8*)(Ab_ + (e ^ ((r & 7) << 3)));  \
                }                                                                \
            if (READB) {                                                         \
                _Pragma("unroll")                                                \
                for (int n = 0; n < 4; ++n)                                      \
                    _Pragma("unroll")                                            \
                    for (int kk = 0; kk < 2; ++kk) {                             \
                        const int e = (wn * 64 + n * 16 + r) * 64 + kk * 32 + kq * 8; \
                        bf[n][kk] = *(const bf16x8*)(Bb_ + (e ^ ((r & 7) << 3))); \
                    }                                                            \
            }                                                                    \
            STAGE_STMT                                                           \
            VM_STMT                                                              \
            __builtin_amdgcn_s_barrier();                                        \
            asm volatile("s_waitcnt lgkmcnt(0)" ::: "memory");                   \
            __builtin_amdgcn_sched_barrier(0);                                   \
            __builtin_amdgcn_s_setprio(1);                                       \
            _Pragma("unroll")                                                    \
            for (int mm = 0; mm < 2; ++mm)                                       \
                _Pragma("unroll")                                                \
                for (int n = 0; n < 4; ++n)                                      \
                    _Pragma("unroll")                                            \
                    for (int kk = 0; kk < 2; ++kk)                               \
                        acc[(q) * 2 + mm][n] = __builtin_amdgcn_mfma_f32_16x16x32_bf16( \
                            af_[mm][kk], bf[n][kk], acc[(q) * 2 + mm][n], 0, 0, 0); \
            __builtin_amdgcn_s_setprio(0);                                       \
            __builtin_amdgcn_s_barrier();                                        \
            __builtin_amdgcn_sched_barrier(0);                                   \
        }

    f32x4 acc[8][4] = {};
    const int nt = K >> 6;
    const int niter = nt >> 1;

    STA(0, 0, 0) STA(0, 0, 1) STB(0, 0, 0) STB(0, 0, 1) STB(1, 64, 0) STB(1, 64, 1)
    asm volatile("s_waitcnt vmcnt(4)" ::: "memory");
    __builtin_amdgcn_s_barrier();
    __builtin_amdgcn_sched_barrier(0);

    for (int t = 0; t < niter; ++t) {
        const int k1 = (2 * t + 1) << 6;
        const int k2 = (2 * t + 2) << 6;
        const int k3 = (2 * t + 3) << 6;
        const bool more = (2 * t + 2) < nt;
        bf16x8 bf[4][2];

        PHASE(0, 0, 1, { STA(1, k1, 0) }, {})
        PHASE(0, 1, 0, { STA(1, k1, 1) }, {})
        PHASE(0, 2, 0, { if (more) STB(0, k2, 0) }, {})
        PHASE(0, 3, 0, { if (more) STB(0, k2, 1) },
              { if (more) { asm volatile("s_waitcnt vmcnt(4)" ::: "memory"); }
                else      { asm volatile("s_waitcnt vmcnt(0)" ::: "memory"); } })
        PHASE(1, 0, 1, { if (more) STA(0, k2, 0) }, {})
        PHASE(1, 1, 0, { if (more) STA(0, k2, 1) }, {})
        PHASE(1, 2, 0, { if (more) STB(1, k3, 0) }, {})
        PHASE(1, 3, 0, { if (more) STB(1, k3, 1) },
              { if (more) { asm volatile("s_waitcnt vmcnt(4)" ::: "memory"); } })
    }
    #undef PHASE
    #undef STA
    #undef STB

    const int orow = tileM + wm * 128 + kq * 4;
    const int ocol = tileN + wn * 64 + r;
    if (OUTF32) {
        float* C = (float*)Cv;
        #pragma unroll
        for (int n = 0; n < 4; ++n) {
            float bv = bias[ocol + n * 16];
            #pragma unroll
            for (int m = 0; m < 8; ++m)
                #pragma unroll
                for (int j = 0; j < 4; ++j)
                    C[(size_t)(orow + m * 16 + j) * ldc + ocol + n * 16] = acc[m][n][j] + bv;
        }
    } else {
        bf16_t* C = (bf16_t*)Cv;
        #pragma unroll
        for (int m = 0; m < 8; ++m)
            #pragma unroll
            for (int n = 0; n < 4; ++n)
                #pragma unroll
                for (int j = 0; j < 4; ++j)
                    C[(size_t)(orow + m * 16 + j) * ldc + ocol + n * 16] = (bf16_t)acc[m][n][j];
    }
}

// ---------------- causal flash attention (R3/R7 body, unpaired grid) ----------
__device__ __forceinline__ void attn_qtile(
    const bf16_t* __restrict__ Q, const bf16_t* __restrict__ Kp,
    const bf16_t* __restrict__ Vp, bf16_t* __restrict__ Op,
    bf16_t* __restrict__ P_lds, int qbase, int lane)
{
    const int r  = lane & 15;
    const int kq = lane >> 4;

    bf16x8 qf[2][2];
    #pragma unroll
    for (int m = 0; m < 2; ++m)
        #pragma unroll
        for (int kk = 0; kk < 2; ++kk)
            qf[m][kk] = *(const bf16x8*)(Q + (size_t)(qbase + m * 16 + r) * NQKV + kk * 32 + kq * 8);

    f32x4 o[2][8] = {};
    float mst[2][4], lst[2][4];
    #pragma unroll
    for (int m = 0; m < 2; ++m)
        #pragma unroll
        for (int j = 0; j < 4; ++j) { mst[m][j] = -INFINITY; lst[m][j] = 0.0f; }

    const int nfull  = qbase >> 6;
    const int ntiles = (qbase + 95) >> 6;

    for (int t = 0; t < ntiles; ++t) {
        const int kvb = t * 64;
        f32x4 s[2][4] = {};
        #pragma unroll
        for (int n = 0; n < 4; ++n) {
            bf16x8 kf0 = *(const bf16x8*)(Kp + (size_t)(kvb + n * 16 + r) * NQKV + kq * 8);
            bf16x8 kf1 = *(const bf16x8*)(Kp + (size_t)(kvb + n * 16 + r) * NQKV + 32 + kq * 8);
            #pragma unroll
            for (int m = 0; m < 2; ++m) {
                s[m][n] = __builtin_amdgcn_mfma_f32_16x16x32_bf16(qf[m][0], kf0, s[m][n], 0, 0, 0);
                s[m][n] = __builtin_amdgcn_mfma_f32_16x16x32_bf16(qf[m][1], kf1, s[m][n], 0, 0, 0);
            }
        }
        if (t >= nfull) {
            #pragma unroll
            for (int m = 0; m < 2; ++m)
                #pragma unroll
                for (int n = 0; n < 4; ++n)
                    #pragma unroll
                    for (int j = 0; j < 4; ++j) {
                        int kc = kvb + n * 16 + r;
                        int qr = qbase + m * 16 + kq * 4 + j;
                        if (kc > qr) s[m][n][j] = -1e30f;
                    }
        }
        float mx[2][4];
        #pragma unroll
        for (int m = 0; m < 2; ++m)
            #pragma unroll
            for (int j = 0; j < 4; ++j) {
                float v = fmaxf(fmaxf(s[m][0][j], s[m][1][j]), fmaxf(s[m][2][j], s[m][3][j]));
                #pragma unroll
                for (int d = 1; d < 16; d <<= 1) v = fmaxf(v, __shfl_xor(v, d, 64));
                mx[m][j] = v;
            }
        bool need = false;
        #pragma unroll
        for (int m = 0; m < 2; ++m)
            #pragma unroll
            for (int j = 0; j < 4; ++j) need |= (mx[m][j] > mst[m][j] + 8.0f);
        if (__ballot(need)) {
            #pragma unroll
            for (int m = 0; m < 2; ++m)
                #pragma unroll
                for (int j = 0; j < 4; ++j) {
                    float mnew  = fmaxf(mst[m][j], mx[m][j]);
                    float alpha = __expf(mst[m][j] - mnew);
                    lst[m][j] *= alpha;
                    mst[m][j]  = mnew;
                    #pragma unroll
                    for (int n = 0; n < 8; ++n) o[m][n][j] *= alpha;
                }
        }
        #pragma unroll
        for (int m = 0; m < 2; ++m)
            #pragma unroll
            for (int j = 0; j < 4; ++j) {
                float rs = 0.0f;
                const int row = m * 16 + kq * 4 + j;
                #pragma unroll
                for (int n = 0; n < 4; ++n) {
                    float pv = __expf(s[m][n][j] - mst[m][j]);
                    rs += pv;
                    const int c = (n * 16 + r) ^ ((row & 7) << 3);
                    P_lds[row * 64 + c] = (bf16_t)pv;
                }
                #pragma unroll
                for (int d = 1; d < 16; d <<= 1) rs += __shfl_xor(rs, d, 64);
                lst[m][j] += rs;
            }
        __syncthreads();
        bf16x8 pf[2][2];
        #pragma unroll
        for (int m = 0; m < 2; ++m)
            #pragma unroll
            for (int kk = 0; kk < 2; ++kk) {
                const int e = (m * 16 + r) * 64 + kk * 32 + kq * 8;
                pf[m][kk] = *(const bf16x8*)(P_lds + (e ^ ((r & 7) << 3)));
            }
        #pragma unroll
        for (int n = 0; n < 8; ++n) {
            #pragma unroll
            for (int kk = 0; kk < 2; ++kk) {
                bf16x8 vf = *(const bf16x8*)(Vp + (size_t)(n * 16 + r) * MROWS + kvb + kk * 32 + kq * 8);
                #pragma unroll
                for (int m = 0; m < 2; ++m)
                    o[m][n] = __builtin_amdgcn_mfma_f32_16x16x32_bf16(pf[m][kk], vf, o[m][n], 0, 0, 0);
            }
        }
        __syncthreads();
    }

    #pragma unroll
    for (int m = 0; m < 2; ++m)
        #pragma unroll
        for (int j = 0; j < 4; ++j) {
            float inv = 1.0f / lst[m][j];
            int row = m * 16 + kq * 4 + j;
            #pragma unroll
            for (int n = 0; n < 8; ++n)
                Op[(size_t)(qbase + row) * HVD + n * 16 + r] = (bf16_t)(o[m][n][j] * inv);
        }
}

// Unpaired: 64 one-tile blocks per (h,b); heavy tiles first (reversed index).
// All 2048 one-wave blocks co-resident -> 2 waves/SIMD TLP; body unchanged.
__global__ __launch_bounds__(64)
void attn_kernel(const bf16_t* __restrict__ qkv, const bf16_t* __restrict__ Vt,
                 bf16_t* __restrict__ O)
{
    __shared__ __align__(16) bf16_t P_lds[32 * 64];
    const int lane = threadIdx.x;
    const int qt = 63 - (int)blockIdx.x;   // heavy first
    const int h = blockIdx.y;
    const int b = blockIdx.z;

    const bf16_t* Q  = qkv + (size_t)(b * S_) * NQKV + h * 64;
    const bf16_t* Kp = qkv + (size_t)(b * S_) * NQKV + R_ + h * 64;
    const bf16_t* Vp = Vt + (size_t)(h * VD_) * MROWS + b * S_;
    bf16_t* Op = O + (size_t)(b * S_) * HVD + h * VD_;

    attn_qtile(Q, Kp, Vp, Op, P_lds, qt * 32, lane);
}

extern "C" void kernel_launch(void* const* d_in, const int* in_sizes, int n_in,
                              void* d_out, int out_size, void* d_ws, size_t ws_size,
                              hipStream_t stream) {
    const float* x   = (const float*)d_in[0];
    const float* Wq  = (const float*)d_in[1];
    const float* Wkv = (const float*)d_in[2];
    const float* Wvb = (const float*)d_in[3];
    const float* Wo  = (const float*)d_in[4];
    const float* bo  = (const float*)d_in[5];

    // scratch in d_out (dead before final GEMM writes it)
    char* oc = (char*)d_out;
    bf16_t* xb     = (bf16_t*)oc;                    // 4096*7168*2 = 58,720,256 B
    bf16_t* Wqkv_b = (bf16_t*)(oc + 58720256);       // 2048*7168*2 = 29,360,128 B
    // scratch in d_ws
    char* ws = (char*)d_ws;
    bf16_t* qkv_b  = (bf16_t*)ws;                    // 4096*2048*2 = 16,777,216
    bf16_t* Wvb_b  = (bf16_t*)(ws + 16777216);       // 2048*1024*2 =  4,194,304
    bf16_t* Vt_b   = (bf16_t*)(ws + 20971520);       // 2048*4096*2 = 16,777,216
    bf16_t* attn_b = (bf16_t*)(ws + 37748736);       // 4096*2048*2 = 16,777,216
    bf16_t* Wo_b   = (bf16_t*)(ws + 54525952);       // 7168*2048*2 = 29,360,128

    const float inv_scale = 0.047245559f;            // 1/sqrt(448)

    // fused conversion: 60,817,408 f32 elems / 8 per thread / 256 per block
    cvt_fused<<<29696, 256, 0, stream>>>(x, Wq, Wkv, Wvb, Wo,
                                         xb, Wqkv_b, Wvb_b, Wo_b, inv_scale);

    // GEMM1: qkv_lat[4096][2048] = x @ [Wq*s | Wkv]^T   (K=7168)  [128^2, R8 schedule]
    gemm_bt<0><<<dim3(16, 32), 256, 0, stream>>>(xb, D_, Wqkv_b, D_, qkv_b, NQKV, nullptr, D_);
    // GEMM2: Vt[2048][4096] = Wvb @ kv_lat^T            (K=1024)
    gemm_bt<0><<<dim3(32, 16), 256, 0, stream>>>(Wvb_b, R_, qkv_b + R_, NQKV, Vt_b, MROWS, nullptr, R_);
    // attention -> attn_b[4096][2048]  (unpaired, heavy-first, 2048 blocks)
    attn_kernel<<<dim3(64, H_, B_), 64, 0, stream>>>(qkv_b, Vt_b, attn_b);
    // GEMM4: out[4096][7168] = attn @ Wo^T + bo  (K=2048)  [256^2, 8-phase schedule]
    gemm_bt256p<1><<<dim3(28, 16), 512, 0, stream>>>(attn_b, HVD, Wo_b, HVD, d_out, D_, bo, HVD);
}

// Round 16
// 487.290 us; speedup vs baseline: 1.2015x; 1.2015x over previous
//
#include <hip/hip_runtime.h>
#include <hip/hip_bf16.h>

typedef __bf16 bf16_t;
typedef __attribute__((ext_vector_type(8))) __bf16 bf16x8;
typedef __attribute__((ext_vector_type(4))) __bf16 bf16x4;
typedef __attribute__((ext_vector_type(4))) float f32x4;

#define B_ 2
#define S_ 2048
#define D_ 7168
#define R_ 1024
#define H_ 16
#define VD_ 128
#define MROWS 4096   // B_*S_
#define NQKV 2048    // fused q|kv cols
#define HVD 2048     // H_*VD_

// ---------------- async global->LDS, 16B per lane ----------------
__device__ __forceinline__ void gload_lds16(const bf16_t* g, bf16_t* l) {
    __builtin_amdgcn_global_load_lds(
        (const __attribute__((address_space(1))) unsigned int*)(g),
        (__attribute__((address_space(3))) unsigned int*)(l),
        16, 0, 0);
}

// ---------------- fused f32 -> bf16 conversion, all 5 tensors, 1 launch -------
__global__ __launch_bounds__(256)
void cvt_fused(const float* __restrict__ x,  const float* __restrict__ Wq,
               const float* __restrict__ Wkv, const float* __restrict__ Wvb,
               const float* __restrict__ Wo,
               bf16_t* __restrict__ xb, bf16_t* __restrict__ Wqkv_b,
               bf16_t* __restrict__ Wvb_b, bf16_t* __restrict__ Wo_b,
               float inv_scale)
{
    const long c = ((long)blockIdx.x * 256 + threadIdx.x);   // chunk of 8
    const long e = c * 8;                                    // element index
    const float* src; bf16_t* dst; long off; float scale = 1.0f;
    if (e < 29360128L) {                 // x -> xb
        src = x;   dst = xb;              off = e;
    } else if (e < 36700160L) {          // Wq -> Wqkv_b[0:] (scaled)
        src = Wq;  dst = Wqkv_b;          off = e - 29360128L; scale = inv_scale;
    } else if (e < 44040192L) {          // Wkv -> Wqkv_b[7340032:]
        src = Wkv; dst = Wqkv_b + 7340032; off = e - 36700160L;
    } else if (e < 46137344L) {          // Wvb -> Wvb_b
        src = Wvb; dst = Wvb_b;           off = e - 44040192L;
    } else {                             // Wo -> Wo_b
        src = Wo;  dst = Wo_b;            off = e - 46137344L;
    }
    f32x4 v0 = *(const f32x4*)(src + off);
    f32x4 v1 = *(const f32x4*)(src + off + 4);
    bf16x8 o;
    o[0] = (bf16_t)(v0[0] * scale); o[1] = (bf16_t)(v0[1] * scale);
    o[2] = (bf16_t)(v0[2] * scale); o[3] = (bf16_t)(v0[3] * scale);
    o[4] = (bf16_t)(v1[0] * scale); o[5] = (bf16_t)(v1[1] * scale);
    o[6] = (bf16_t)(v1[2] * scale); o[7] = (bf16_t)(v1[3] * scale);
    *(bf16x8*)(dst + off) = o;
}

// ---------------- bf16 GEMM 128x128 (R8 schedule: best for 4-wave) ------------
template<int OUTF32>
__global__ __launch_bounds__(256)
void gemm_bt(const bf16_t* __restrict__ A, int lda,
             const bf16_t* __restrict__ Bt, int ldb,
             void* __restrict__ Cv, int ldc,
             const float* __restrict__ bias, int K)
{
    __shared__ __align__(16) bf16_t As[2][128 * 64];
    __shared__ __align__(16) bf16_t Bs[2][128 * 64];
    const int tid  = threadIdx.x;
    const int lane = tid & 63;
    const int wave = tid >> 6;
    const int tileM = blockIdx.y * 128;
    const int tileN = blockIdx.x * 128;
    const int wr = (wave >> 1) * 64;
    const int wc = (wave & 1) * 64;
    const int r  = lane & 15;
    const int kq = lane >> 4;

    const bf16_t* Ag = A  + (size_t)tileM * lda;
    const bf16_t* Bg = Bt + (size_t)tileN * ldb;

    int srow[4], scol[4], slin[4];
    #pragma unroll
    for (int i = 0; i < 4; ++i) {
        slin[i] = (i * 256 + tid) * 8;
        srow[i] = slin[i] >> 6;
        scol[i] = (slin[i] & 63) ^ ((srow[i] & 7) << 3);  // inverse-swizzled source
    }

    #define ISSUE_TILE(buf, k0)                                                  \
        {                                                                        \
            _Pragma("unroll")                                                    \
            for (int i = 0; i < 4; ++i) {                                        \
                gload_lds16(Ag + (size_t)srow[i] * lda + (k0) + scol[i], As[buf] + slin[i]); \
                gload_lds16(Bg + (size_t)srow[i] * ldb + (k0) + scol[i], Bs[buf] + slin[i]); \
            }                                                                    \
        }

    f32x4 acc[4][4] = {};
    const int nt = K >> 6;

    ISSUE_TILE(0, 0)
    ISSUE_TILE(1, 64)
    asm volatile("s_waitcnt vmcnt(8)" ::: "memory");
    __builtin_amdgcn_s_barrier();
    __builtin_amdgcn_sched_barrier(0);

    for (int t = 0; t < nt; ++t) {
        const int cur = t & 1;
        const bf16_t* Ab = As[cur];
        const bf16_t* Bb = Bs[cur];

        bf16x8 af[4][2], bfr[4][2];
        #pragma unroll
        for (int m = 0; m < 4; ++m)
            #pragma unroll
            for (int kk = 0; kk < 2; ++kk) {
                const int e = (wr + m * 16 + r) * 64 + kk * 32 + kq * 8;
                af[m][kk] = *(const bf16x8*)(Ab + (e ^ ((r & 7) << 3)));
            }
        #pragma unroll
        for (int n = 0; n < 4; ++n)
            #pragma unroll
            for (int kk = 0; kk < 2; ++kk) {
                const int e = (wc + n * 16 + r) * 64 + kk * 32 + kq * 8;
                bfr[n][kk] = *(const bf16x8*)(Bb + (e ^ ((r & 7) << 3)));
            }
        __builtin_amdgcn_s_setprio(1);
        #pragma unroll
        for (int kk = 0; kk < 2; ++kk)
            #pragma unroll
            for (int m = 0; m < 4; ++m)
                #pragma unroll
                for (int n = 0; n < 4; ++n)
                    acc[m][n] = __builtin_amdgcn_mfma_f32_16x16x32_bf16(af[m][kk], bfr[n][kk], acc[m][n], 0, 0, 0);
        __builtin_amdgcn_s_setprio(0);

        __builtin_amdgcn_s_barrier();
        __builtin_amdgcn_sched_barrier(0);
        if (t + 2 < nt) {
            ISSUE_TILE(cur, (t + 2) << 6)
            asm volatile("s_waitcnt vmcnt(8)" ::: "memory");
        } else {
            asm volatile("s_waitcnt vmcnt(0)" ::: "memory");
        }
        __builtin_amdgcn_s_barrier();
        __builtin_amdgcn_sched_barrier(0);
    }
    #undef ISSUE_TILE

    const int orow = tileM + wr + kq * 4;
    const int ocol = tileN + wc + r;
    if (OUTF32) {
        float* C = (float*)Cv;
        #pragma unroll
        for (int n = 0; n < 4; ++n) {
            float bv = bias[ocol + n * 16];
            #pragma unroll
            for (int m = 0; m < 4; ++m)
                #pragma unroll
                for (int j = 0; j < 4; ++j)
                    C[(size_t)(orow + m * 16 + j) * ldc + ocol + n * 16] = acc[m][n][j] + bv;
        }
    } else {
        bf16_t* C = (bf16_t*)Cv;
        #pragma unroll
        for (int m = 0; m < 4; ++m)
            #pragma unroll
            for (int n = 0; n < 4; ++n)
                #pragma unroll
                for (int j = 0; j < 4; ++j)
                    C[(size_t)(orow + m * 16 + j) * ldc + ocol + n * 16] = (bf16_t)acc[m][n][j];
    }
}

// ---------------- bf16 GEMM 256x256, 8-phase m201-style schedule --------------
template<int OUTF32>
__global__ __launch_bounds__(512, 2)
void gemm_bt256p(const bf16_t* __restrict__ A, int lda,
                 const bf16_t* __restrict__ Bt, int ldb,
                 void* __restrict__ Cv, int ldc,
                 const float* __restrict__ bias, int K)
{
    __shared__ __align__(16) bf16_t As[2][256 * 64];
    __shared__ __align__(16) bf16_t Bs[2][256 * 64];
    const int tid  = threadIdx.x;
    const int lane = tid & 63;
    const int wave = tid >> 6;
    const int wm = wave >> 2;          // 0..1 -> M offset wm*128
    const int wn = wave & 3;           // 0..3 -> N offset wn*64
    const int tileM = blockIdx.y * 256;
    const int tileN = blockIdx.x * 256;
    const int r  = lane & 15;
    const int kq = lane >> 4;

    const bf16_t* Ag = A  + (size_t)tileM * lda;
    const bf16_t* Bg = Bt + (size_t)tileN * ldb;

    int sr[2], sc[2], sl[2];
    #pragma unroll
    for (int i = 0; i < 2; ++i) {
        sl[i] = (i * 512 + tid) * 8;
        sr[i] = sl[i] >> 6;
        sc[i] = (sl[i] & 63) ^ ((sr[i] & 7) << 3);   // inverse-swizzled source
    }

    #define STA(buf, k0, h)                                                      \
        { _Pragma("unroll")                                                      \
          for (int i = 0; i < 2; ++i)                                            \
              gload_lds16(Ag + (size_t)((h) * 128 + sr[i]) * lda + (k0) + sc[i], \
                          As[buf] + (h) * 8192 + sl[i]); }
    #define STB(buf, k0, h)                                                      \
        { _Pragma("unroll")                                                      \
          for (int i = 0; i < 2; ++i)                                            \
              gload_lds16(Bg + (size_t)((h) * 128 + sr[i]) * ldb + (k0) + sc[i], \
                          Bs[buf] + (h) * 8192 + sl[i]); }

    #define PHASE(buf, q, READB, STAGE_STMT, VM_STMT)                            \
        {                                                                        \
            const bf16_t* Ab_ = As[buf];                                         \
            const bf16_t* Bb_ = Bs[buf];                                         \
            bf16x8 af_[2][2];                                                    \
            _Pragma("unroll")                                                    \
            for (int mm = 0; mm < 2; ++mm)                                       \
                _Pragma("unroll")                                                \
                for (int kk = 0; kk < 2; ++kk) {                                 \
                    const int e = (wm * 128 + ((q) * 2 + mm) * 16 + r) * 64 + kk * 32 + kq * 8; \
                    af_[mm][kk] = *(const bf16x8*)(Ab_ + (e ^ ((r & 7) << 3)));  \
                }                                                                \
            if (READB) {                                                         \
                _Pragma("unroll")                                                \
                for (int n = 0; n < 4; ++n)                                      \
                    _Pragma("unroll")                                            \
                    for (int kk = 0; kk < 2; ++kk) {                             \
                        const int e = (wn * 64 + n * 16 + r) * 64 + kk * 32 + kq * 8; \
                        bf[n][kk] = *(const bf16x8*)(Bb_ + (e ^ ((r & 7) << 3))); \
                    }                                                            \
            }                                                                    \
            STAGE_STMT                                                           \
            VM_STMT                                                              \
            __builtin_amdgcn_s_barrier();                                        \
            asm volatile("s_waitcnt lgkmcnt(0)" ::: "memory");                   \
            __builtin_amdgcn_sched_barrier(0);                                   \
            __builtin_amdgcn_s_setprio(1);                                       \
            _Pragma("unroll")                                                    \
            for (int mm = 0; mm < 2; ++mm)                                       \
                _Pragma("unroll")                                                \
                for (int n = 0; n < 4; ++n)                                      \
                    _Pragma("unroll")                                            \
                    for (int kk = 0; kk < 2; ++kk)                               \
                        acc[(q) * 2 + mm][n] = __builtin_amdgcn_mfma_f32_16x16x32_bf16( \
                            af_[mm][kk], bf[n][kk], acc[(q) * 2 + mm][n], 0, 0, 0); \
            __builtin_amdgcn_s_setprio(0);                                       \
            __builtin_amdgcn_s_barrier();                                        \
            __builtin_amdgcn_sched_barrier(0);                                   \
        }

    f32x4 acc[8][4] = {};
    const int nt = K >> 6;
    const int niter = nt >> 1;

    STA(0, 0, 0) STA(0, 0, 1) STB(0, 0, 0) STB(0, 0, 1) STB(1, 64, 0) STB(1, 64, 1)
    asm volatile("s_waitcnt vmcnt(4)" ::: "memory");
    __builtin_amdgcn_s_barrier();
    __builtin_amdgcn_sched_barrier(0);

    for (int t = 0; t < niter; ++t) {
        const int k1 = (2 * t + 1) << 6;
        const int k2 = (2 * t + 2) << 6;
        const int k3 = (2 * t + 3) << 6;
        const bool more = (2 * t + 2) < nt;
        bf16x8 bf[4][2];

        PHASE(0, 0, 1, { STA(1, k1, 0) }, {})
        PHASE(0, 1, 0, { STA(1, k1, 1) }, {})
        PHASE(0, 2, 0, { if (more) STB(0, k2, 0) }, {})
        PHASE(0, 3, 0, { if (more) STB(0, k2, 1) },
              { if (more) { asm volatile("s_waitcnt vmcnt(4)" ::: "memory"); }
                else      { asm volatile("s_waitcnt vmcnt(0)" ::: "memory"); } })
        PHASE(1, 0, 1, { if (more) STA(0, k2, 0) }, {})
        PHASE(1, 1, 0, { if (more) STA(0, k2, 1) }, {})
        PHASE(1, 2, 0, { if (more) STB(1, k3, 0) }, {})
        PHASE(1, 3, 0, { if (more) STB(1, k3, 1) },
              { if (more) { asm volatile("s_waitcnt vmcnt(4)" ::: "memory"); } })
    }
    #undef PHASE
    #undef STA
    #undef STB

    const int orow = tileM + wm * 128 + kq * 4;
    const int ocol = tileN + wn * 64 + r;
    if (OUTF32) {
        float* C = (float*)Cv;
        #pragma unroll
        for (int n = 0; n < 4; ++n) {
            float bv = bias[ocol + n * 16];
            #pragma unroll
            for (int m = 0; m < 8; ++m)
                #pragma unroll
                for (int j = 0; j < 4; ++j)
                    C[(size_t)(orow + m * 16 + j) * ldc + ocol + n * 16] = acc[m][n][j] + bv;
        }
    } else {
        bf16_t* C = (bf16_t*)Cv;
        #pragma unroll
        for (int m = 0; m < 8; ++m)
            #pragma unroll
            for (int n = 0; n < 4; ++n)
                #pragma unroll
                for (int j = 0; j < 4; ++j)
                    C[(size_t)(orow + m * 16 + j) * ldc + ocol + n * 16] = (bf16_t)acc[m][n][j];
    }
}

// ---------------- causal flash attention (R3/R7 proven local optimum) ----------
__device__ __forceinline__ void attn_qtile(
    const bf16_t* __restrict__ Q, const bf16_t* __restrict__ Kp,
    const bf16_t* __restrict__ Vp, bf16_t* __restrict__ Op,
    bf16_t* __restrict__ P_lds, int qbase, int lane)
{
    const int r  = lane & 15;
    const int kq = lane >> 4;

    bf16x8 qf[2][2];
    #pragma unroll
    for (int m = 0; m < 2; ++m)
        #pragma unroll
        for (int kk = 0; kk < 2; ++kk)
            qf[m][kk] = *(const bf16x8*)(Q + (size_t)(qbase + m * 16 + r) * NQKV + kk * 32 + kq * 8);

    f32x4 o[2][8] = {};
    float mst[2][4], lst[2][4];
    #pragma unroll
    for (int m = 0; m < 2; ++m)
        #pragma unroll
        for (int j = 0; j < 4; ++j) { mst[m][j] = -INFINITY; lst[m][j] = 0.0f; }

    const int nfull  = qbase >> 6;
    const int ntiles = (qbase + 95) >> 6;

    for (int t = 0; t < ntiles; ++t) {
        const int kvb = t * 64;
        f32x4 s[2][4] = {};
        #pragma unroll
        for (int n = 0; n < 4; ++n) {
            bf16x8 kf0 = *(const bf16x8*)(Kp + (size_t)(kvb + n * 16 + r) * NQKV + kq * 8);
            bf16x8 kf1 = *(const bf16x8*)(Kp + (size_t)(kvb + n * 16 + r) * NQKV + 32 + kq * 8);
            #pragma unroll
            for (int m = 0; m < 2; ++m) {
                s[m][n] = __builtin_amdgcn_mfma_f32_16x16x32_bf16(qf[m][0], kf0, s[m][n], 0, 0, 0);
                s[m][n] = __builtin_amdgcn_mfma_f32_16x16x32_bf16(qf[m][1], kf1, s[m][n], 0, 0, 0);
            }
        }
        if (t >= nfull) {
            #pragma unroll
            for (int m = 0; m < 2; ++m)
                #pragma unroll
                for (int n = 0; n < 4; ++n)
                    #pragma unroll
                    for (int j = 0; j < 4; ++j) {
                        int kc = kvb + n * 16 + r;
                        int qr = qbase + m * 16 + kq * 4 + j;
                        if (kc > qr) s[m][n][j] = -1e30f;
                    }
        }
        float mx[2][4];
        #pragma unroll
        for (int m = 0; m < 2; ++m)
            #pragma unroll
            for (int j = 0; j < 4; ++j) {
                float v = fmaxf(fmaxf(s[m][0][j], s[m][1][j]), fmaxf(s[m][2][j], s[m][3][j]));
                #pragma unroll
                for (int d = 1; d < 16; d <<= 1) v = fmaxf(v, __shfl_xor(v, d, 64));
                mx[m][j] = v;
            }
        bool need = false;
        #pragma unroll
        for (int m = 0; m < 2; ++m)
            #pragma unroll
            for (int j = 0; j < 4; ++j) need |= (mx[m][j] > mst[m][j] + 8.0f);
        if (__ballot(need)) {
            #pragma unroll
            for (int m = 0; m < 2; ++m)
                #pragma unroll
                for (int j = 0; j < 4; ++j) {
                    float mnew  = fmaxf(mst[m][j], mx[m][j]);
                    float alpha = __expf(mst[m][j] - mnew);
                    lst[m][j] *= alpha;
                    mst[m][j]  = mnew;
                    #pragma unroll
                    for (int n = 0; n < 8; ++n) o[m][n][j] *= alpha;
                }
        }
        #pragma unroll
        for (int m = 0; m < 2; ++m)
            #pragma unroll
            for (int j = 0; j < 4; ++j) {
                float rs = 0.0f;
                const int row = m * 16 + kq * 4 + j;
                #pragma unroll
                for (int n = 0; n < 4; ++n) {
                    float pv = __expf(s[m][n][j] - mst[m][j]);
                    rs += pv;
                    const int c = (n * 16 + r) ^ ((row & 7) << 3);
                    P_lds[row * 64 + c] = (bf16_t)pv;
                }
                #pragma unroll
                for (int d = 1; d < 16; d <<= 1) rs += __shfl_xor(rs, d, 64);
                lst[m][j] += rs;
            }
        __syncthreads();
        bf16x8 pf[2][2];
        #pragma unroll
        for (int m = 0; m < 2; ++m)
            #pragma unroll
            for (int kk = 0; kk < 2; ++kk) {
                const int e = (m * 16 + r) * 64 + kk * 32 + kq * 8;
                pf[m][kk] = *(const bf16x8*)(P_lds + (e ^ ((r & 7) << 3)));
            }
        #pragma unroll
        for (int n = 0; n < 8; ++n) {
            #pragma unroll
            for (int kk = 0; kk < 2; ++kk) {
                bf16x8 vf = *(const bf16x8*)(Vp + (size_t)(n * 16 + r) * MROWS + kvb + kk * 32 + kq * 8);
                #pragma unroll
                for (int m = 0; m < 2; ++m)
                    o[m][n] = __builtin_amdgcn_mfma_f32_16x16x32_bf16(pf[m][kk], vf, o[m][n], 0, 0, 0);
            }
        }
        __syncthreads();
    }

    #pragma unroll
    for (int m = 0; m < 2; ++m)
        #pragma unroll
        for (int j = 0; j < 4; ++j) {
            float inv = 1.0f / lst[m][j];
            int row = m * 16 + kq * 4 + j;
            #pragma unroll
            for (int n = 0; n < 8; ++n)
                Op[(size_t)(qbase + row) * HVD + n * 16 + r] = (bf16_t)(o[m][n][j] * inv);
        }
}

// Block = 1 wave; pair-balanced: block p handles q-tiles 63-p and p.
__global__ __launch_bounds__(64)
void attn_kernel(const bf16_t* __restrict__ qkv, const bf16_t* __restrict__ Vt,
                 bf16_t* __restrict__ O)
{
    __shared__ __align__(16) bf16_t P_lds[32 * 64];
    const int lane = threadIdx.x;
    const int p = blockIdx.x;
    const int h = blockIdx.y;
    const int b = blockIdx.z;

    const bf16_t* Q  = qkv + (size_t)(b * S_) * NQKV + h * 64;
    const bf16_t* Kp = qkv + (size_t)(b * S_) * NQKV + R_ + h * 64;
    const bf16_t* Vp = Vt + (size_t)(h * VD_) * MROWS + b * S_;
    bf16_t* Op = O + (size_t)(b * S_) * HVD + h * VD_;

    attn_qtile(Q, Kp, Vp, Op, P_lds, (63 - p) * 32, lane);  // heavy half
    attn_qtile(Q, Kp, Vp, Op, P_lds, p * 32, lane);         // light half
}

extern "C" void kernel_launch(void* const* d_in, const int* in_sizes, int n_in,
                              void* d_out, int out_size, void* d_ws, size_t ws_size,
                              hipStream_t stream) {
    const float* x   = (const float*)d_in[0];
    const float* Wq  = (const float*)d_in[1];
    const float* Wkv = (const float*)d_in[2];
    const float* Wvb = (const float*)d_in[3];
    const float* Wo  = (const float*)d_in[4];
    const float* bo  = (const float*)d_in[5];

    // scratch in d_out (dead before final GEMM writes it)
    char* oc = (char*)d_out;
    bf16_t* xb     = (bf16_t*)oc;                    // 4096*7168*2 = 58,720,256 B
    bf16_t* Wqkv_b = (bf16_t*)(oc + 58720256);       // 2048*7168*2 = 29,360,128 B
    // scratch in d_ws
    char* ws = (char*)d_ws;
    bf16_t* qkv_b  = (bf16_t*)ws;                    // 4096*2048*2 = 16,777,216
    bf16_t* Wvb_b  = (bf16_t*)(ws + 16777216);       // 2048*1024*2 =  4,194,304
    bf16_t* Vt_b   = (bf16_t*)(ws + 20971520);       // 2048*4096*2 = 16,777,216
    bf16_t* attn_b = (bf16_t*)(ws + 37748736);       // 4096*2048*2 = 16,777,216
    bf16_t* Wo_b   = (bf16_t*)(ws + 54525952);       // 7168*2048*2 = 29,360,128

    const float inv_scale = 0.047245559f;            // 1/sqrt(448)

    // fused conversion: 60,817,408 f32 elems / 8 per thread / 256 per block
    cvt_fused<<<29696, 256, 0, stream>>>(x, Wq, Wkv, Wvb, Wo,
                                         xb, Wqkv_b, Wvb_b, Wo_b, inv_scale);

    // GEMM1: qkv_lat[4096][2048] = x @ [Wq*s | Wkv]^T   (K=7168)  [128^2, R8 schedule]
    gemm_bt<0><<<dim3(16, 32), 256, 0, stream>>>(xb, D_, Wqkv_b, D_, qkv_b, NQKV, nullptr, D_);
    // GEMM2: Vt[2048][4096] = Wvb @ kv_lat^T            (K=1024)
    gemm_bt<0><<<dim3(32, 16), 256, 0, stream>>>(Wvb_b, R_, qkv_b + R_, NQKV, Vt_b, MROWS, nullptr, R_);
    // attention -> attn_b[4096][2048]  (pair-balanced, R3 structure)
    attn_kernel<<<dim3(32, H_, B_), 64, 0, stream>>>(qkv_b, Vt_b, attn_b);
    // GEMM4: out[4096][7168] = attn @ Wo^T + bo  (K=2048)  [256^2, 8-phase schedule]
    gemm_bt256p<1><<<dim3(28, 16), 512, 0, stream>>>(attn_b, HVD, Wo_b, HVD, d_out, D_, bo, HVD);
}